// Round 11
// baseline (743.291 us; speedup 1.0000x reference)
//
#include <hip/hip_runtime.h>
#include <hip/hip_bf16.h>

// DFFN fused implementation. R17: spectral conv v4 — kill the spill for real.
// R16 post-mortem: WRITE 1.09GB/FETCH 604MB scratch, VGPR_Count 64. Cause:
// both conv loops were #pragma unroll -> after full unroll the compiler
// HOISTS all independent table loads (g128T 128 floats + Bt/Bt2p frags)
// across the body; live set >> 128-VGPR cap of launch_bounds(256,4); the
// allocator collapses to 64 VGPRs + scratch-everything. Fix:
//  (1) chunk loop FORCED ROLLED (#pragma unroll 1) — loads can't hoist
//      across a loop-carried iteration; live set = acc_o(64) + ~35 temps.
//  (2) launch_bounds(256,3) — ~170 VGPR budget, 3 blocks/CU (R12's proven
//      occupancy regime).
// Math identical to R15/R16 (both PASSED, absmax 2.44e-4).
// Pipeline: proj_in(1x1 MFMA hi/lo) -> spectral 8x8 circular conv (MFMA;
// o_c = P^T(g_c*(P y_c)), P = shared real 2D-DFT basis, exact 8-value LUT;
// k-slot permutation baked into Bt2p) -> dw3x3 -> GELU gate -> proj_out(MFMA).
// s: bf16 [b][c2/8][h][w][8ch].

#define BATCH 4
#define CIN   64
#define C2    256
#define HH    256
#define WW    256
#define HW    (HH*WW)

using bf16 = __hip_bfloat16;
typedef short bf16x8 __attribute__((ext_vector_type(8)));
typedef float f32x4  __attribute__((ext_vector_type(4)));

__device__ __forceinline__ unsigned f2bf_bits(float v){
    unsigned u = __float_as_uint(v);
    return (u + 0x7fffu + ((u >> 16) & 1u)) >> 16;          // RNE
}
__device__ __forceinline__ float bfbits2f(unsigned hu){ return __uint_as_float(hu << 16); }

__device__ __forceinline__ void unpack8(uint4 v, float* f) {
    unsigned a0 = v.x, a1 = v.y, a2 = v.z, a3 = v.w;
    f[0] = __uint_as_float(a0 << 16); f[1] = __uint_as_float(a0 & 0xffff0000u);
    f[2] = __uint_as_float(a1 << 16); f[3] = __uint_as_float(a1 & 0xffff0000u);
    f[4] = __uint_as_float(a2 << 16); f[5] = __uint_as_float(a2 & 0xffff0000u);
    f[6] = __uint_as_float(a3 << 16); f[7] = __uint_as_float(a3 & 0xffff0000u);
}

// GELU(v) = 0.5*v*(1+erf(v/sqrt2)), erf via A&S 7.1.26 (|eps| <= 1.5e-7).
__device__ __forceinline__ float gelu_exact(float v){
    float z  = v * 0.7071067811865476f;
    float ax = fabsf(z);
    float t  = 1.0f / fmaf(0.3275911f, ax, 1.0f);
    float p  = t * fmaf(t, fmaf(t, fmaf(t, fmaf(t, 1.061405429f, -1.453152027f),
                                        1.421413741f), -0.284496736f), 0.254829592f);
    float e  = __expf(-ax*ax);
    float er = fmaf(-p, e, 1.0f);                // erf(|z|)
    er = copysignf(er, z);
    return 0.5f * v * (1.0f + er);
}

// ---------------------------------------------------------------------------
// K0 (16 blocks): build
//  - Bt   [128 J][64 u] hi/lo bf16: J<64 = cos th, J>=64 = sin th,
//    th = (pi/4)*((m*a + v*b) mod 8), J&63 = m*8+v, u = a*8+b. LUT-exact.
//  - Bt2p [64 u][128 P] hi/lo bf16: PERMUTED transpose — within each chunk of
//    32, position p holds J = chunk*32 + ((p>>2)&1)*16 + (p>>3)*4 + (p&3),
//    matching k1's register k-slot map p = quad*8 + jt*4 + r.
//  - g128T[128 J][256 c] f32: G_c[m][v]/64, Hermitian-extended rfft2 filter.
//  - whi/wlo (w_in hi/lo split), wob (w_out bf16).
// ---------------------------------------------------------------------------
__global__ void k_precompute(const float* __restrict__ F,
                             const float* __restrict__ w_in,
                             const float* __restrict__ w_out,
                             unsigned short* __restrict__ Bth,
                             unsigned short* __restrict__ Btl,
                             unsigned short* __restrict__ Bt2ph,
                             unsigned short* __restrict__ Bt2pl,
                             float* __restrict__ g128T,
                             unsigned short* __restrict__ whi,
                             unsigned short* __restrict__ wlo,
                             unsigned short* __restrict__ wob)
{
    const int tid = threadIdx.x, bid = blockIdx.x;
    const int step = 16*256;
    const float R = 0.7071067811865476f;
    const float C8[8] = {1.f, R, 0.f, -R, -1.f, -R, 0.f, R};
    const float S8[8] = {0.f, R, 1.f, R, 0.f, -R, -1.f, -R};

    // w_in split
    for (int e = bid*256 + tid; e < 256*64; e += step) {
        float v = w_in[e];
        unsigned hu = f2bf_bits(v);
        whi[e] = (unsigned short)hu;
        wlo[e] = (unsigned short)f2bf_bits(v - bfbits2f(hu));
    }
    // w_out bf16
    for (int e = bid*256 + tid; e < 64*128; e += step)
        wob[e] = (unsigned short)f2bf_bits(w_out[e]);

    // Bt: [J][u]
    for (int e = bid*256 + tid; e < 128*64; e += step) {
        const int J = e >> 6, u = e & 63;
        const int j = J & 63, m = j >> 3, v = j & 7;
        const int a = u >> 3, b2 = u & 7;
        const int idx = (m*a + v*b2) & 7;
        const float val = (J < 64) ? C8[idx] : S8[idx];
        unsigned hu = f2bf_bits(val);
        Bth[e] = (unsigned short)hu;
        Btl[e] = (unsigned short)f2bf_bits(val - bfbits2f(hu));
    }

    // Bt2p: [u][P], P = chunk*32 + p, value = basis(J(p), u)
    for (int e = bid*256 + tid; e < 64*128; e += step) {
        const int u = e >> 7, P = e & 127;
        const int chunk = P >> 5, p = P & 31;
        const int Jloc = ((p >> 2) & 1)*16 + (p >> 3)*4 + (p & 3);
        const int J = chunk*32 + Jloc;
        const int j = J & 63, m = j >> 3, v = j & 7;
        const int a = u >> 3, b2 = u & 7;
        const int idx = (m*a + v*b2) & 7;
        const float val = (J < 64) ? C8[idx] : S8[idx];
        unsigned hu = f2bf_bits(val);
        Bt2ph[e] = (unsigned short)hu;
        Bt2pl[e] = (unsigned short)f2bf_bits(val - bfbits2f(hu));
    }

    // per-channel spectral gains, transposed [J][c]
    for (int e = bid*256 + tid; e < 128*256; e += step) {
        const int J = e >> 8, c = e & 255;
        const int j = J & 63, m = j >> 3, v = j & 7;
        const float Fv = (v <= 4) ? F[c*40 + m*5 + v]
                                  : F[c*40 + ((8-m)&7)*5 + (8-v)];
        g128T[e] = Fv * 0.015625f;       // /64
    }
}

// ---------------------------------------------------------------------------
// K1: per (b, h, 64-col run):
//  proj_in via MFMA (hi/lo bf16, 16 acc tiles in regs) ->
//  yC[c][u] bf16 in LDS (slot-swizzled) ->
//  conv: ct unrolled x chunk ROLLED (#pragma unroll 1):
//    G1t: acc2t[jt] = mfma(A=Bt hi/lo, B=yC)        (col=c=n16)
//    g-apply + bf16 hi/lo pack (elem jt*4+r)        (pure VALU, static idx)
//    G2:  acc_o[ct][ut] += mfma(A=Bt2p hi/lo, B=z)
//  -> ST[u][c] -> chunk-blocked bf16 store s[b][c2/8][h][w][8ch].
// LDS 33KB; launch_bounds(256,3) ~170 VGPR budget, 3 blocks/CU.
// ---------------------------------------------------------------------------
#define SMEM_HW  16512      // 33,024 B: yC [0,16384) during conv; ST [0,16512) after

__global__ __launch_bounds__(256, 3) void k1_proj_circ(
    const float* __restrict__ x,
    const unsigned short* __restrict__ whi,
    const unsigned short* __restrict__ wlo,
    const float* __restrict__ b_in,
    const unsigned short* __restrict__ Bth,
    const unsigned short* __restrict__ Btl,
    const unsigned short* __restrict__ Bt2ph,
    const unsigned short* __restrict__ Bt2pl,
    const float* __restrict__ g128T,
    bf16* __restrict__ s)
{
    __shared__ __align__(16) unsigned short smem[SMEM_HW];
    unsigned short* xs_hi = smem;            // [64 px][64 c] swizzled, 8 KB
    unsigned short* xs_lo = smem + 4096;     // 8 KB (inside yC region)

    const int tid = threadIdx.x;
    const int bid = blockIdx.x;
    const int run = bid & 3;
    const int h   = (bid >> 2) & 255;
    const int b   = bid >> 10;

    const float* xb = x + (long)b * CIN * HW + h * WW + run * 64;

    // stage x tile (64 cin x 64 px), hi/lo split, [px][cin] XOR-swizzled
#pragma unroll
    for (int i = 0; i < 16; ++i) {
        int e = i*256 + tid;
        int c = e >> 6, col = e & 63;
        float v = xb[(long)c * HW + col];
        unsigned hu = f2bf_bits(v);
        unsigned lu = f2bf_bits(v - bfbits2f(hu));
        const int sw = col*64 + (c ^ ((col & 7) << 3));
        xs_hi[sw] = (unsigned short)hu;
        xs_lo[sw] = (unsigned short)lu;
    }
    __syncthreads();

    const int wv = tid >> 6, lane = tid & 63;
    const int quad = lane >> 4, n16 = lane & 15;
    const int cb = wv*64;                    // wave's channel base

    // ---- proj_in MFMAs: acc[nt][mt], D row = px-in-tile, col = c2-in-tile
    f32x4 acc[4][4];
#pragma unroll
    for (int nt = 0; nt < 4; ++nt)
#pragma unroll
        for (int mt = 0; mt < 4; ++mt) acc[nt][mt] = (f32x4){0.f,0.f,0.f,0.f};

#pragma unroll
    for (int nt = 0; nt < 4; ++nt) {
        const int c2 = cb + nt*16 + n16;
#pragma unroll
        for (int k = 0; k < 2; ++k) {
            const bf16x8 bh = *(const bf16x8*)&whi[c2*64 + k*32 + quad*8];
            const bf16x8 bl = *(const bf16x8*)&wlo[c2*64 + k*32 + quad*8];
#pragma unroll
            for (int mt = 0; mt < 4; ++mt) {
                const int o = (mt*16 + n16)*64 + (((k*4 + quad) ^ (n16 & 7)) << 3);
                const bf16x8 a_h = *(const bf16x8*)&xs_hi[o];
                const bf16x8 a_l = *(const bf16x8*)&xs_lo[o];
                acc[nt][mt] = __builtin_amdgcn_mfma_f32_16x16x32_bf16(a_h, bh, acc[nt][mt], 0, 0, 0);
                acc[nt][mt] = __builtin_amdgcn_mfma_f32_16x16x32_bf16(a_l, bh, acc[nt][mt], 0, 0, 0);
                acc[nt][mt] = __builtin_amdgcn_mfma_f32_16x16x32_bf16(a_h, bl, acc[nt][mt], 0, 0, 0);
            }
        }
    }
    __syncthreads();     // all proj reads of xs done; yC may overwrite region

    // ---- write yC[c][u] bf16 (+bias), slot-swizzled:
    //      hw = c*64 + (((u>>3) ^ (c&7))<<3) + (u&7)
#pragma unroll
    for (int nt = 0; nt < 4; ++nt) {
        const int c2 = cb + nt*16 + n16;
        const float bv = b_in[c2];
#pragma unroll
        for (int mt = 0; mt < 4; ++mt)
#pragma unroll
            for (int r = 0; r < 4; ++r) {
                const int u = mt*16 + quad*4 + r;
                smem[c2*64 + (((u >> 3) ^ (c2 & 7)) << 3) + (u & 7)] =
                    (unsigned short)f2bf_bits(acc[nt][mt][r] + bv);
            }
    }
    // no barrier: chunk pipeline below reads only this wave's c-rows

    // ---- spectral conv: ct unrolled, chunk ROLLED (prevents load hoisting)
    f32x4 acc_o[4][4];                       // [ct][ut]: row=u, col=c
#pragma unroll
    for (int ct = 0; ct < 4; ++ct)
#pragma unroll
        for (int ut = 0; ut < 4; ++ut) acc_o[ct][ut] = (f32x4){0.f,0.f,0.f,0.f};

#pragma unroll
    for (int ct = 0; ct < 4; ++ct) {
        const int c = cb + ct*16 + n16;
#pragma unroll 1
        for (int chunk = 0; chunk < 4; ++chunk) {
            const int jbase = chunk*32;

            // G1t: Zt[J][c] = sum_u Bt[J][u] * yC[c][u]
            f32x4 acc2t[2];                  // [jt]
            acc2t[0] = (f32x4){0.f,0.f,0.f,0.f};
            acc2t[1] = (f32x4){0.f,0.f,0.f,0.f};
#pragma unroll
            for (int ks = 0; ks < 2; ++ks) {
                const bf16x8 yB = *(const bf16x8*)&smem[c*64 + (((ks*4 + quad) ^ (n16 & 7)) << 3)];
#pragma unroll
                for (int jt = 0; jt < 2; ++jt) {
                    const int J = jbase + jt*16 + n16;
                    const bf16x8 ah = *(const bf16x8*)&Bth[J*64 + ks*32 + quad*8];
                    const bf16x8 al = *(const bf16x8*)&Btl[J*64 + ks*32 + quad*8];
                    acc2t[jt] = __builtin_amdgcn_mfma_f32_16x16x32_bf16(ah, yB, acc2t[jt], 0, 0, 0);
                    acc2t[jt] = __builtin_amdgcn_mfma_f32_16x16x32_bf16(al, yB, acc2t[jt], 0, 0, 0);
                }
            }

            // g-apply + in-register bf16 hi/lo pack (elem e = jt*4 + r)
            bf16x8 vh, vl;
#pragma unroll
            for (int jt = 0; jt < 2; ++jt)
#pragma unroll
                for (int r = 0; r < 4; ++r) {
                    const int Jg = jbase + jt*16 + quad*4 + r;
                    const float z = acc2t[jt][r] * g128T[Jg*256 + c];
                    const unsigned hz = f2bf_bits(z);
                    vh[jt*4 + r] = (short)hz;
                    vl[jt*4 + r] = (short)f2bf_bits(z - bfbits2f(hz));
                }

            // G2: o^T[u][c] += sum_p Bt2p[u][p] * z[c][p]
#pragma unroll
            for (int ut = 0; ut < 4; ++ut) {
                const int u = ut*16 + n16;
                const bf16x8 a2h = *(const bf16x8*)&Bt2ph[u*128 + jbase + quad*8];
                const bf16x8 a2l = *(const bf16x8*)&Bt2pl[u*128 + jbase + quad*8];
                acc_o[ct][ut] = __builtin_amdgcn_mfma_f32_16x16x32_bf16(a2h, vh, acc_o[ct][ut], 0, 0, 0);
                acc_o[ct][ut] = __builtin_amdgcn_mfma_f32_16x16x32_bf16(a2h, vl, acc_o[ct][ut], 0, 0, 0);
                acc_o[ct][ut] = __builtin_amdgcn_mfma_f32_16x16x32_bf16(a2l, vh, acc_o[ct][ut], 0, 0, 0);
            }
        }
    }
    __syncthreads();     // all waves done reading yC before ST overwrites

    // ---- ST[u][c] staging (stride 258): u = ut*16+quad*4+r, c = cb+ct*16+n16
#pragma unroll
    for (int ct = 0; ct < 4; ++ct)
#pragma unroll
        for (int ut = 0; ut < 4; ++ut)
#pragma unroll
            for (int r = 0; r < 4; ++r) {
                const int c = cb + ct*16 + n16;
                const int u = ut*16 + quad*4 + r;
                smem[u*258 + c] = (unsigned short)f2bf_bits(acc_o[ct][ut][r]);
            }
    __syncthreads();

    const int u   = tid & 63;
    const int rg2 = tid >> 6;
#pragma unroll
    for (int pass = 0; pass < 8; ++pass) {
        const int chunk = pass*4 + rg2;                       // 0..31
        const unsigned* yp = (const unsigned*)&smem[u*258 + chunk*8];
        uint4 val = make_uint4(yp[0], yp[1], yp[2], yp[3]);
        *(uint4*)(s + ((((long)(b*32 + chunk)*HH + h)*WW) + run*64 + u)*8) = val;
    }
}

// ---------------------------------------------------------------------------
// K2 (unchanged from R12): dw3x3 + bias -> GELU gate -> MFMA proj_out.
// ---------------------------------------------------------------------------
__global__ __launch_bounds__(256) void k2_dw_gelu_out(
    const bf16* __restrict__ s, const float* __restrict__ w_dw,
    const float* __restrict__ b_dw,
    const unsigned short* __restrict__ wob,
    const float* __restrict__ b_out, float* __restrict__ out)
{
    __shared__ __align__(16) unsigned short gs[64*136];   // 17 KB, [px][c]

    const int tid = threadIdx.x;
    const int l   = ((blockIdx.x & 7) << 9) | (blockIdx.x >> 3);  // XCD swizzle
    const int run = l & 3;
    const int h   = (l >> 2) & 255;
    const int b   = l >> 10;
    const int wl  = tid & 63, rg = tid >> 6;
    const int w   = run*64 + wl;

#pragma unroll
    for (int i = 0; i < 4; ++i) {
        const int chunk = __builtin_amdgcn_readfirstlane(rg + 4*i);   // 0..15, uniform
        const int c0 = chunk*8;                                        // 0..120
        const bf16* pb1 = s + (long)(b*32 + chunk     ) * HW * 8;
        const bf16* pb2 = s + (long)(b*32 + chunk + 16) * HW * 8;

        float t1[8], t2[8];
#pragma unroll
        for (int j = 0; j < 8; ++j) { t1[j] = b_dw[c0+j]; t2[j] = b_dw[c0+128+j]; }

#pragma unroll
        for (int dy = 0; dy < 3; ++dy) {
            const int hy = h + dy - 1;
            if ((unsigned)hy >= HH) continue;          // wave-uniform
#pragma unroll
            for (int dx = 0; dx < 3; ++dx) {
                const int wx = w + dx - 1;
                if ((unsigned)wx < WW) {               // diverges only at image edge
                    const int off = (hy*WW + wx) << 3; // element offset, fits int
                    uint4 v1 = *(const uint4*)(pb1 + off);
                    uint4 v2 = *(const uint4*)(pb2 + off);
                    float f1[8], f2[8];
                    unpack8(v1, f1); unpack8(v2, f2);
#pragma unroll
                    for (int j = 0; j < 8; ++j) {
                        t1[j] += f1[j] * w_dw[(c0+j)*9       + dy*3 + dx];
                        t2[j] += f2[j] * w_dw[(c0+128+j)*9   + dy*3 + dx];
                    }
                }
            }
        }
        unsigned r4[4];
#pragma unroll
        for (int j = 0; j < 4; ++j) {
            float ga = gelu_exact(t1[2*j])   * t2[2*j];
            float gb = gelu_exact(t1[2*j+1]) * t2[2*j+1];
            r4[j] = f2bf_bits(ga) | (f2bf_bits(gb) << 16);
        }
        *(uint4*)&gs[wl*136 + c0] = make_uint4(r4[0], r4[1], r4[2], r4[3]);
    }
    __syncthreads();

    const int quad = wl >> 4, n16 = wl & 15;
    const int px   = rg*16 + n16;

    f32x4 acc[4];
#pragma unroll
    for (int mt = 0; mt < 4; ++mt) acc[mt] = (f32x4){0.f,0.f,0.f,0.f};

#pragma unroll
    for (int ks = 0; ks < 4; ++ks) {
        const bf16x8 bfrag = *(const bf16x8*)&gs[px*136 + ks*32 + quad*8];
#pragma unroll
        for (int mt = 0; mt < 4; ++mt) {
            const bf16x8 afrag = *(const bf16x8*)&wob[(mt*16 + n16)*128 + ks*32 + quad*8];
            acc[mt] = __builtin_amdgcn_mfma_f32_16x16x32_bf16(afrag, bfrag, acc[mt], 0, 0, 0);
        }
    }

    float* op = out + (long)b * CIN * HW + h * WW + run*64 + rg*16 + n16;
#pragma unroll
    for (int mt = 0; mt < 4; ++mt)
#pragma unroll
        for (int r = 0; r < 4; ++r) {
            const int c_out = mt*16 + quad*4 + r;
            op[(long)c_out * HW] = acc[mt][r] + b_out[c_out];
        }
}

// ---------------------------------------------------------------------------
extern "C" void kernel_launch(void* const* d_in, const int* in_sizes, int n_in,
                              void* d_out, int out_size, void* d_ws, size_t ws_size,
                              hipStream_t stream) {
    const float* x     = (const float*)d_in[0];
    const float* w_in  = (const float*)d_in[1];
    const float* b_in  = (const float*)d_in[2];
    const float* ff    = (const float*)d_in[3];
    const float* w_dw  = (const float*)d_in[4];
    const float* b_dw  = (const float*)d_in[5];
    const float* w_out = (const float*)d_in[6];
    const float* b_out = (const float*)d_in[7];
    float* out = (float*)d_out;

    // d_ws layout (proven R12 footprint): wob [64K,80K) | s [80K, +128MB)
    char* ws = (char*)d_ws;
    unsigned short* wob = (unsigned short*)(ws + 65536);
    bf16*           s   = (bf16*)         (ws + 81920);

    // k1-only tables in d_out (64MB): k1 reads them; k1 retires (stream order)
    // before k2 overwrites out. Pattern proven R6-R16.
    char* ob = (char*)d_out;
    unsigned short* whi   = (unsigned short*)(ob);            // 32 KB
    unsigned short* wlo   = (unsigned short*)(ob + 32768);    // 32 KB
    unsigned short* Bth   = (unsigned short*)(ob + 65536);    // 16 KB
    unsigned short* Btl   = (unsigned short*)(ob + 81920);    // 16 KB
    unsigned short* Bt2ph = (unsigned short*)(ob + 98304);    // 16 KB
    unsigned short* Bt2pl = (unsigned short*)(ob + 114688);   // 16 KB
    float*          g128T = (float*)        (ob + 131072);    // 128 KB

    hipLaunchKernelGGL(k_precompute,   dim3(16),   dim3(256), 0, stream,
                       ff, w_in, w_out, Bth, Btl, Bt2ph, Bt2pl, g128T, whi, wlo, wob);
    hipLaunchKernelGGL(k1_proj_circ,   dim3(4096), dim3(256), 0, stream,
                       x, whi, wlo, b_in, Bth, Btl, Bt2ph, Bt2pl, g128T, s);
    hipLaunchKernelGGL(k2_dw_gelu_out, dim3(4096), dim3(256), 0, stream,
                       s, w_dw, b_dw, wob, b_out, out);
}

// Round 12
// 356.007 us; speedup vs baseline: 2.0879x; 2.0879x over previous
//
#include <hip/hip_runtime.h>
#include <hip/hip_bf16.h>

// DFFN fused implementation. R18: revert to R12 structure (best: 376us) +
// per-thread radix-2 8x8 real FFT for the circular conv.
// Spectral-MFMA arc (R13-R17) abandoned: its basis-table traffic is
// structurally hostile (LDS round-trip / VGPR spill / 16-line gathers in a
// rolled loop). R12's conv is VALU-issue-bound (73% busy, 4096 FMA + 512 LDS
// reads/thread). The FFT does the same operator in ~1100 VALU ops + 64 LDS
// reads + 40 coalesced gain loads: row rFFT8 -> 5 col cFFT8 -> real gain
// (g = F/64, x2 for v=1..3 folded at k0) -> conj-FFT-conj inverse -> inverse
// row. Twiddles in {0,+-1,+-0.7071} exact. Verified symbolically (DC and
// single-cosine; ones-filter => identity). Statically indexed, ~11KB code,
// peak ~112 VGPR under launch_bounds(256,4)'s 128 cap.
// Pipeline: proj_in(1x1 MFMA hi/lo bf16) -> per-channel 8x8 circular conv
// (FFT, == rfft2*filter*irfft2 on flat-reshaped patches) -> dw3x3 -> GELU
// gate -> proj_out(1x1 MFMA). s: bf16 [b][c2/8][h][w][8ch].

#define BATCH 4
#define CIN   64
#define C2    256
#define HH    256
#define WW    256
#define HW    (HH*WW)

using bf16 = __hip_bfloat16;
typedef short bf16x8 __attribute__((ext_vector_type(8)));
typedef float f32x4  __attribute__((ext_vector_type(4)));

__device__ __forceinline__ unsigned f2bf_bits(float v){
    unsigned u = __float_as_uint(v);
    return (u + 0x7fffu + ((u >> 16) & 1u)) >> 16;          // RNE
}
__device__ __forceinline__ float bfbits2f(unsigned hu){ return __uint_as_float(hu << 16); }

__device__ __forceinline__ void unpack8(uint4 v, float* f) {
    unsigned a0 = v.x, a1 = v.y, a2 = v.z, a3 = v.w;
    f[0] = __uint_as_float(a0 << 16); f[1] = __uint_as_float(a0 & 0xffff0000u);
    f[2] = __uint_as_float(a1 << 16); f[3] = __uint_as_float(a1 & 0xffff0000u);
    f[4] = __uint_as_float(a2 << 16); f[5] = __uint_as_float(a2 & 0xffff0000u);
    f[6] = __uint_as_float(a3 << 16); f[7] = __uint_as_float(a3 & 0xffff0000u);
}

// GELU(v) = 0.5*v*(1+erf(v/sqrt2)), erf via A&S 7.1.26 (|eps| <= 1.5e-7).
__device__ __forceinline__ float gelu_exact(float v){
    float z  = v * 0.7071067811865476f;
    float ax = fabsf(z);
    float t  = 1.0f / fmaf(0.3275911f, ax, 1.0f);
    float p  = t * fmaf(t, fmaf(t, fmaf(t, fmaf(t, 1.061405429f, -1.453152027f),
                                        1.421413741f), -0.284496736f), 0.254829592f);
    float e  = __expf(-ax*ax);
    float er = fmaf(-p, e, 1.0f);                // erf(|z|)
    er = copysignf(er, z);
    return 0.5f * v * (1.0f + er);
}

// Complex 8-point DIT FFT (W = e^{-2pi i/8}), in-place, natural order.
// All indices literal -> SROA to registers after inlining.
__device__ __forceinline__ void fft8c(float* re, float* im){
    const float R2 = 0.70710678118654752f;
    float t0r=re[0]+re[4], t0i=im[0]+im[4];
    float t1r=re[0]-re[4], t1i=im[0]-im[4];
    float t2r=re[2]+re[6], t2i=im[2]+im[6];
    float t3r=re[2]-re[6], t3i=im[2]-im[6];
    float E0r=t0r+t2r, E0i=t0i+t2i;
    float E2r=t0r-t2r, E2i=t0i-t2i;
    float E1r=t1r+t3i, E1i=t1i-t3r;          // t1 - i t3
    float E3r=t1r-t3i, E3i=t1i+t3r;          // t1 + i t3
    float u0r=re[1]+re[5], u0i=im[1]+im[5];
    float u1r=re[1]-re[5], u1i=im[1]-im[5];
    float u2r=re[3]+re[7], u2i=im[3]+im[7];
    float u3r=re[3]-re[7], u3i=im[3]-im[7];
    float O0r=u0r+u2r, O0i=u0i+u2i;
    float O2r=u0r-u2r, O2i=u0i-u2i;
    float O1r=u1r+u3i, O1i=u1i-u3r;
    float O3r=u1r-u3i, O3i=u1i+u3r;
    float w1r=R2*(O1r+O1i), w1i=R2*(O1i-O1r);    // W^1 O1, W^1 = r(1-i)
    float w3r=R2*(O3i-O3r), w3i=-R2*(O3r+O3i);   // W^3 O3, W^3 = -r(1+i)
    re[0]=E0r+O0r; im[0]=E0i+O0i;
    re[4]=E0r-O0r; im[4]=E0i-O0i;
    re[1]=E1r+w1r; im[1]=E1i+w1i;
    re[5]=E1r-w1r; im[5]=E1i-w1i;
    re[2]=E2r+O2i; im[2]=E2i-O2r;                // E2 - i O2
    re[6]=E2r-O2i; im[6]=E2i+O2r;
    re[3]=E3r+w3r; im[3]=E3i+w3i;
    re[7]=E3r-w3r; im[7]=E3i-w3i;
}

// ---------------------------------------------------------------------------
// K0 (16 blocks): (a) gain table gT[j=m*5+v][256 c] = F[c][m][v]/64, doubled
//     for v in {1,2,3} (Hermitian middle-bin weight of irfft);
//     (b) hi/lo bf16 split of w_in -> whi/wlo; (c) bf16 w_out table wob.
// ---------------------------------------------------------------------------
__global__ void k_precompute(const float* __restrict__ F,
                             const float* __restrict__ w_in,
                             const float* __restrict__ w_out,
                             float* __restrict__ gT,
                             unsigned short* __restrict__ whi,
                             unsigned short* __restrict__ wlo,
                             unsigned short* __restrict__ wob)
{
    const int tid = threadIdx.x, bid = blockIdx.x;
    const int step = 16*256;

    // (b) w_in split: flat, coalesced
    for (int e = bid*256 + tid; e < 256*64; e += step) {
        float v = w_in[e];
        unsigned hu = f2bf_bits(v);
        whi[e] = (unsigned short)hu;
        wlo[e] = (unsigned short)f2bf_bits(v - bfbits2f(hu));
    }
    // (c) w_out bf16 table: flat, coalesced
    for (int e = bid*256 + tid; e < 64*128; e += step)
        wob[e] = (unsigned short)f2bf_bits(w_out[e]);

    // (a) gain table, transposed [j][c]
    for (int e = bid*256 + tid; e < 40*256; e += step) {
        const int j = e >> 8, c = e & 255;       // j = m*5+v
        const int v = j % 5;
        const float sc = (v == 0 || v == 4) ? 0.015625f : 0.03125f;
        gT[e] = F[c*40 + j] * sc;
    }
}

// ---------------------------------------------------------------------------
// K1: per (b, h, 64-col run): proj_in via MFMA (hi/lo bf16, all 16 acc tiles
// in regs), ysT bf16 in LDS, per-thread 8x8 FFT conv (channel = tid), bf16
// chunk-blocked store s[b][c2/8][h][w][8ch].
// LDS union 33KB -> 4 blocks/CU; launch_bounds(256,4) caps 128 VGPR.
// ---------------------------------------------------------------------------
__global__ __launch_bounds__(256, 4) void k1_proj_circ(
    const float* __restrict__ x,
    const unsigned short* __restrict__ whi,
    const unsigned short* __restrict__ wlo,
    const float* __restrict__ b_in,
    const float* __restrict__ gT,
    bf16* __restrict__ s)
{
    // union: [0,4096)hw = xs_hi, [4096,8192)hw = xs_lo during staging+MFMA;
    // whole [0, 64*258)hw = ysT afterwards.
    __shared__ __align__(16) unsigned short smem[64*258];   // 33,024 B
    unsigned short* xs_hi = smem;
    unsigned short* xs_lo = smem + 4096;
    unsigned short* ysT   = smem;

    const int tid = threadIdx.x;
    const int bid = blockIdx.x;
    const int run = bid & 3;
    const int h   = (bid >> 2) & 255;
    const int b   = bid >> 10;

    const float* xb = x + (long)b * CIN * HW + h * WW + run * 64;

    // stage x tile (64 cin x 64 px), hi/lo bf16 split, [px][cin] XOR-swizzled
#pragma unroll
    for (int i = 0; i < 16; ++i) {
        int e = i*256 + tid;
        int c = e >> 6, col = e & 63;
        float v = xb[(long)c * HW + col];
        unsigned hu = f2bf_bits(v);
        unsigned lu = f2bf_bits(v - bfbits2f(hu));
        const int sw = col*64 + (c ^ ((col & 7) << 3));
        xs_hi[sw] = (unsigned short)hu;
        xs_lo[sw] = (unsigned short)lu;
    }
    __syncthreads();

    const int wv = tid >> 6, lane = tid & 63;
    const int quad = lane >> 4, n16 = lane & 15;

    // proj MFMAs: all 4 nt-tiles, accumulators held in registers.
    f32x4 acc[4][4];
#pragma unroll
    for (int nt = 0; nt < 4; ++nt)
#pragma unroll
        for (int mt = 0; mt < 4; ++mt) acc[nt][mt] = (f32x4){0.f,0.f,0.f,0.f};

#pragma unroll
    for (int nt = 0; nt < 4; ++nt) {
        const int c2 = wv*64 + nt*16 + n16;
#pragma unroll
        for (int k = 0; k < 2; ++k) {
            const bf16x8 bh = *(const bf16x8*)&whi[c2*64 + k*32 + quad*8];
            const bf16x8 bl = *(const bf16x8*)&wlo[c2*64 + k*32 + quad*8];
#pragma unroll
            for (int mt = 0; mt < 4; ++mt) {
                const int o = (mt*16 + n16)*64 + (((k*4 + quad) ^ (n16 & 7)) << 3);
                const bf16x8 a_h = *(const bf16x8*)&xs_hi[o];
                const bf16x8 a_l = *(const bf16x8*)&xs_lo[o];
                acc[nt][mt] = __builtin_amdgcn_mfma_f32_16x16x32_bf16(a_h, bh, acc[nt][mt], 0, 0, 0);
                acc[nt][mt] = __builtin_amdgcn_mfma_f32_16x16x32_bf16(a_l, bh, acc[nt][mt], 0, 0, 0);
                acc[nt][mt] = __builtin_amdgcn_mfma_f32_16x16x32_bf16(a_h, bl, acc[nt][mt], 0, 0, 0);
            }
        }
    }
    __syncthreads();        // xs region dead; safe to overwrite with ysT

    // write ysT[u][c2] (stride 258) + bias
#pragma unroll
    for (int nt = 0; nt < 4; ++nt) {
        const int c2 = wv*64 + nt*16 + n16;
        const float bv = b_in[c2];
#pragma unroll
        for (int mt = 0; mt < 4; ++mt)
#pragma unroll
            for (int r = 0; r < 4; ++r) {
                int u = mt*16 + quad*4 + r;          // D row = quad*4 + reg
                ysT[u*258 + c2] = (unsigned short)f2bf_bits(acc[nt][mt][r] + bv);
            }
    }
    __syncthreads();

    // ---- per-thread 8x8 FFT conv: thread = channel tid (column private).
    float yr[8][8];
#pragma unroll
    for (int u = 0; u < 64; ++u)
        yr[u >> 3][u & 7] = bfbits2f((unsigned)ysT[u*258 + tid]);

    const float R2 = 0.70710678118654752f;

    // row forward rFFT8: yr[a] := [X0, X1r, X1i, X2r, X2i, X3r, X3i, X4]
#pragma unroll
    for (int a = 0; a < 8; ++a) {
        float x0=yr[a][0],x1=yr[a][1],x2=yr[a][2],x3=yr[a][3],
              x4=yr[a][4],x5=yr[a][5],x6=yr[a][6],x7=yr[a][7];
        float t0=x0+x4, t1=x0-x4, t2=x2+x6, t3=x2-x6;
        float u0=x1+x5, u1=x1-x5, u2=x3+x7, u3=x3-x7;
        float E0=t0+t2, E2=t0-t2, O0=u0+u2, O2=u0-u2;
        float rm=R2*(u1-u3), rp=R2*(u1+u3);
        yr[a][0]=E0+O0;                       // X0 (real)
        yr[a][7]=E0-O0;                       // X4 (real)
        yr[a][1]=t1+rm;  yr[a][2]=-t3-rp;     // X1
        yr[a][3]=E2;     yr[a][4]=-O2;        // X2 = E2 - i O2
        yr[a][5]=t1-rm;  yr[a][6]=t3-rp;      // X3
    }

    // columns 0 and 4 (real inputs): fwd cFFT8 -> gain -> inverse (conj trick)
    float tr0[8], tr4[8];
#pragma unroll
    for (int cc = 0; cc < 2; ++cc) {
        float cr[8], ci[8];
#pragma unroll
        for (int a2 = 0; a2 < 8; ++a2) { cr[a2] = yr[a2][cc ? 7 : 0]; ci[a2] = 0.f; }
        fft8c(cr, ci);
#pragma unroll
        for (int m = 0; m < 8; ++m) {
            const float gv = gT[(m*5 + (cc ? 4 : 0))*256 + tid];
            cr[m] = cr[m]*gv; ci[m] = -(ci[m]*gv);     // conj for inverse
        }
        fft8c(cr, ci);
        // T = conj(out): Re(T) = cr (only Re needed for bins 0/4)
#pragma unroll
        for (int a2 = 0; a2 < 8; ++a2) { if (cc) tr4[a2] = cr[a2]; else tr0[a2] = cr[a2]; }
    }

    // columns 1..3 (complex): fwd -> gain -> inverse, in place
#pragma unroll
    for (int v = 1; v <= 3; ++v) {
        float cr[8], ci[8];
#pragma unroll
        for (int a2 = 0; a2 < 8; ++a2) { cr[a2] = yr[a2][2*v-1]; ci[a2] = yr[a2][2*v]; }
        fft8c(cr, ci);
#pragma unroll
        for (int m = 0; m < 8; ++m) {
            const float gv = gT[(m*5 + v)*256 + tid];
            cr[m] = cr[m]*gv; ci[m] = -(ci[m]*gv);     // conj for inverse
        }
        fft8c(cr, ci);
#pragma unroll
        for (int a2 = 0; a2 < 8; ++a2) { yr[a2][2*v-1] = cr[a2]; yr[a2][2*v] = -ci[a2]; }
    }

    // row inverse (real output; x2 middle-bin weight folded into gT)
#pragma unroll
    for (int a = 0; a < 8; ++a) {
        float a0 = tr0[a], a4 = tr4[a];
        float T1r=yr[a][1], T1i=yr[a][2], T2r=yr[a][3], T2i=yr[a][4],
              T3r=yr[a][5], T3i=yr[a][6];
        float A0=a0+a4, A1=a0-a4;
        float Q0=T1r+T3r;
        float Q1=R2*((T1r-T1i)-(T3r+T3i));
        float Q2=T3i-T1i;
        float Q3=R2*((T3r-T3i)-(T1r+T1i));
        float B0=A0+T2r, B2=A0-T2r, B1=A1-T2i, B3=A1+T2i;
        ysT[(a*8+0)*258+tid]=(unsigned short)f2bf_bits(B0+Q0);
        ysT[(a*8+4)*258+tid]=(unsigned short)f2bf_bits(B0-Q0);
        ysT[(a*8+1)*258+tid]=(unsigned short)f2bf_bits(B1+Q1);
        ysT[(a*8+5)*258+tid]=(unsigned short)f2bf_bits(B1-Q1);
        ysT[(a*8+2)*258+tid]=(unsigned short)f2bf_bits(B2+Q2);
        ysT[(a*8+6)*258+tid]=(unsigned short)f2bf_bits(B2-Q2);
        ysT[(a*8+3)*258+tid]=(unsigned short)f2bf_bits(B3+Q3);
        ysT[(a*8+7)*258+tid]=(unsigned short)f2bf_bits(B3-Q3);
    }
    __syncthreads();

    // store: chunk-blocked layout s[b][chunk=c2/8][h][w][8ch]
    const int u   = tid & 63;
    const int rg2 = tid >> 6;          // 0..3
#pragma unroll
    for (int pass = 0; pass < 8; ++pass) {
        const int chunk = pass*4 + rg2;                       // 0..31
        const unsigned* yp = (const unsigned*)&ysT[u*258 + chunk*8];
        uint4 val = make_uint4(yp[0], yp[1], yp[2], yp[3]);
        *(uint4*)(s + ((((long)(b*32 + chunk)*HH + h)*WW) + run*64 + u)*8) = val;
    }
}

// ---------------------------------------------------------------------------
// K2 (unchanged from R12): dw3x3 + bias -> GELU gate -> MFMA proj_out.
// ---------------------------------------------------------------------------
__global__ __launch_bounds__(256) void k2_dw_gelu_out(
    const bf16* __restrict__ s, const float* __restrict__ w_dw,
    const float* __restrict__ b_dw,
    const unsigned short* __restrict__ wob,
    const float* __restrict__ b_out, float* __restrict__ out)
{
    __shared__ __align__(16) unsigned short gs[64*136];   // 17 KB, [px][c]

    const int tid = threadIdx.x;
    const int l   = ((blockIdx.x & 7) << 9) | (blockIdx.x >> 3);  // XCD swizzle
    const int run = l & 3;
    const int h   = (l >> 2) & 255;
    const int b   = l >> 10;
    const int wl  = tid & 63, rg = tid >> 6;
    const int w   = run*64 + wl;

#pragma unroll
    for (int i = 0; i < 4; ++i) {
        const int chunk = __builtin_amdgcn_readfirstlane(rg + 4*i);   // 0..15, uniform
        const int c0 = chunk*8;                                        // 0..120
        const bf16* pb1 = s + (long)(b*32 + chunk     ) * HW * 8;
        const bf16* pb2 = s + (long)(b*32 + chunk + 16) * HW * 8;

        float t1[8], t2[8];
#pragma unroll
        for (int j = 0; j < 8; ++j) { t1[j] = b_dw[c0+j]; t2[j] = b_dw[c0+128+j]; }

#pragma unroll
        for (int dy = 0; dy < 3; ++dy) {
            const int hy = h + dy - 1;
            if ((unsigned)hy >= HH) continue;          // wave-uniform
#pragma unroll
            for (int dx = 0; dx < 3; ++dx) {
                const int wx = w + dx - 1;
                if ((unsigned)wx < WW) {               // diverges only at image edge
                    const int off = (hy*WW + wx) << 3; // element offset, fits int
                    uint4 v1 = *(const uint4*)(pb1 + off);
                    uint4 v2 = *(const uint4*)(pb2 + off);
                    float f1[8], f2[8];
                    unpack8(v1, f1); unpack8(v2, f2);
#pragma unroll
                    for (int j = 0; j < 8; ++j) {
                        t1[j] += f1[j] * w_dw[(c0+j)*9       + dy*3 + dx];
                        t2[j] += f2[j] * w_dw[(c0+128+j)*9   + dy*3 + dx];
                    }
                }
            }
        }
        unsigned r4[4];
#pragma unroll
        for (int j = 0; j < 4; ++j) {
            float ga = gelu_exact(t1[2*j])   * t2[2*j];
            float gb = gelu_exact(t1[2*j+1]) * t2[2*j+1];
            r4[j] = f2bf_bits(ga) | (f2bf_bits(gb) << 16);
        }
        *(uint4*)&gs[wl*136 + c0] = make_uint4(r4[0], r4[1], r4[2], r4[3]);
    }
    __syncthreads();

    const int quad = wl >> 4, n16 = wl & 15;
    const int px   = rg*16 + n16;

    f32x4 acc[4];
#pragma unroll
    for (int mt = 0; mt < 4; ++mt) acc[mt] = (f32x4){0.f,0.f,0.f,0.f};

#pragma unroll
    for (int ks = 0; ks < 4; ++ks) {
        const bf16x8 bfrag = *(const bf16x8*)&gs[px*136 + ks*32 + quad*8];
#pragma unroll
        for (int mt = 0; mt < 4; ++mt) {
            const bf16x8 afrag = *(const bf16x8*)&wob[(mt*16 + n16)*128 + ks*32 + quad*8];
            acc[mt] = __builtin_amdgcn_mfma_f32_16x16x32_bf16(afrag, bfrag, acc[mt], 0, 0, 0);
        }
    }

    float* op = out + (long)b * CIN * HW + h * WW + run*64 + rg*16 + n16;
#pragma unroll
    for (int mt = 0; mt < 4; ++mt)
#pragma unroll
        for (int r = 0; r < 4; ++r) {
            const int c_out = mt*16 + quad*4 + r;
            op[(long)c_out * HW] = acc[mt][r] + b_out[c_out];
        }
}

// ---------------------------------------------------------------------------
extern "C" void kernel_launch(void* const* d_in, const int* in_sizes, int n_in,
                              void* d_out, int out_size, void* d_ws, size_t ws_size,
                              hipStream_t stream) {
    const float* x     = (const float*)d_in[0];
    const float* w_in  = (const float*)d_in[1];
    const float* b_in  = (const float*)d_in[2];
    const float* ff    = (const float*)d_in[3];
    const float* w_dw  = (const float*)d_in[4];
    const float* b_dw  = (const float*)d_in[5];
    const float* w_out = (const float*)d_in[6];
    const float* b_out = (const float*)d_in[7];
    float* out = (float*)d_out;

    // d_ws layout (R12 footprint): gT [0,40K) | wob [64K,80K) | s [80K, +128MB)
    char* ws = (char*)d_ws;
    float*          gT  = (float*)ws;
    unsigned short* wob = (unsigned short*)(ws + 65536);
    bf16*           s   = (bf16*)         (ws + 81920);

    // whi/wlo in d_out: only k1 reads them; k1 retires (stream order) before
    // k2 overwrites out. Pattern proven R6-R17.
    unsigned short* whi = (unsigned short*)d_out;       // 32 KB
    unsigned short* wlo = whi + 256*64;                 // 32 KB

    hipLaunchKernelGGL(k_precompute,   dim3(16),   dim3(256), 0, stream,
                       ff, w_in, w_out, gT, whi, wlo, wob);
    hipLaunchKernelGGL(k1_proj_circ,   dim3(4096), dim3(256), 0, stream,
                       x, whi, wlo, b_in, gT, s);
    hipLaunchKernelGGL(k2_dw_gelu_out, dim3(4096), dim3(256), 0, stream,
                       s, w_dw, b_dw, wob, b_out, out);
}

// Round 13
// 320.690 us; speedup vs baseline: 2.3178x; 1.1101x over previous
//
#include <hip/hip_runtime.h>
#include <hip/hip_bf16.h>

// DFFN fused implementation. R19 = R18 (FFT conv, best 356us) minus the spill.
// R18 post-mortem: k1 214us with VGPR_Count 64, WRITE 291MB (131+160 scratch),
// FETCH 114MB (34+80) -> FFT phase live set (yr 64 + tr0/tr4 16 + cr/ci 16 +
// hoisted gT loads) blew launch_bounds(256,4)'s 128-VGPR cap. Fixes:
//  (1) tr0/tr4 folded into yr[a][0]/yr[a][7] (slots dead after col read;
//      inverse row reads them in place) — -16 regs.
//  (2) launch_bounds(256,3): ~170 VGPR budget, 3 blocks/CU (R12-proven
//      regime) — no spill.
// Math identical to R18 (PASSED, absmax 2.44e-4).
// Pipeline: proj_in(1x1 MFMA hi/lo bf16) -> per-channel 8x8 circular conv
// (per-thread radix-2 real FFT; twiddles in {0,+-1,+-0.7071} exact; gains
// g = F/64 with x2 middle-bin fold) -> dw3x3 -> GELU gate -> proj_out(MFMA).
// s: bf16 [b][c2/8][h][w][8ch].

#define BATCH 4
#define CIN   64
#define C2    256
#define HH    256
#define WW    256
#define HW    (HH*WW)

using bf16 = __hip_bfloat16;
typedef short bf16x8 __attribute__((ext_vector_type(8)));
typedef float f32x4  __attribute__((ext_vector_type(4)));

__device__ __forceinline__ unsigned f2bf_bits(float v){
    unsigned u = __float_as_uint(v);
    return (u + 0x7fffu + ((u >> 16) & 1u)) >> 16;          // RNE
}
__device__ __forceinline__ float bfbits2f(unsigned hu){ return __uint_as_float(hu << 16); }

__device__ __forceinline__ void unpack8(uint4 v, float* f) {
    unsigned a0 = v.x, a1 = v.y, a2 = v.z, a3 = v.w;
    f[0] = __uint_as_float(a0 << 16); f[1] = __uint_as_float(a0 & 0xffff0000u);
    f[2] = __uint_as_float(a1 << 16); f[3] = __uint_as_float(a1 & 0xffff0000u);
    f[4] = __uint_as_float(a2 << 16); f[5] = __uint_as_float(a2 & 0xffff0000u);
    f[6] = __uint_as_float(a3 << 16); f[7] = __uint_as_float(a3 & 0xffff0000u);
}

// GELU(v) = 0.5*v*(1+erf(v/sqrt2)), erf via A&S 7.1.26 (|eps| <= 1.5e-7).
__device__ __forceinline__ float gelu_exact(float v){
    float z  = v * 0.7071067811865476f;
    float ax = fabsf(z);
    float t  = 1.0f / fmaf(0.3275911f, ax, 1.0f);
    float p  = t * fmaf(t, fmaf(t, fmaf(t, fmaf(t, 1.061405429f, -1.453152027f),
                                        1.421413741f), -0.284496736f), 0.254829592f);
    float e  = __expf(-ax*ax);
    float er = fmaf(-p, e, 1.0f);                // erf(|z|)
    er = copysignf(er, z);
    return 0.5f * v * (1.0f + er);
}

// Complex 8-point DIT FFT (W = e^{-2pi i/8}), in-place, natural order.
__device__ __forceinline__ void fft8c(float* re, float* im){
    const float R2 = 0.70710678118654752f;
    float t0r=re[0]+re[4], t0i=im[0]+im[4];
    float t1r=re[0]-re[4], t1i=im[0]-im[4];
    float t2r=re[2]+re[6], t2i=im[2]+im[6];
    float t3r=re[2]-re[6], t3i=im[2]-im[6];
    float E0r=t0r+t2r, E0i=t0i+t2i;
    float E2r=t0r-t2r, E2i=t0i-t2i;
    float E1r=t1r+t3i, E1i=t1i-t3r;          // t1 - i t3
    float E3r=t1r-t3i, E3i=t1i+t3r;          // t1 + i t3
    float u0r=re[1]+re[5], u0i=im[1]+im[5];
    float u1r=re[1]-re[5], u1i=im[1]-im[5];
    float u2r=re[3]+re[7], u2i=im[3]+im[7];
    float u3r=re[3]-re[7], u3i=im[3]-im[7];
    float O0r=u0r+u2r, O0i=u0i+u2i;
    float O2r=u0r-u2r, O2i=u0i-u2i;
    float O1r=u1r+u3i, O1i=u1i-u3r;
    float O3r=u1r-u3i, O3i=u1i+u3r;
    float w1r=R2*(O1r+O1i), w1i=R2*(O1i-O1r);    // W^1 O1
    float w3r=R2*(O3i-O3r), w3i=-R2*(O3r+O3i);   // W^3 O3
    re[0]=E0r+O0r; im[0]=E0i+O0i;
    re[4]=E0r-O0r; im[4]=E0i-O0i;
    re[1]=E1r+w1r; im[1]=E1i+w1i;
    re[5]=E1r-w1r; im[5]=E1i-w1i;
    re[2]=E2r+O2i; im[2]=E2i-O2r;                // E2 - i O2
    re[6]=E2r-O2i; im[6]=E2i+O2r;
    re[3]=E3r+w3r; im[3]=E3i+w3i;
    re[7]=E3r-w3r; im[7]=E3i-w3i;
}

// ---------------------------------------------------------------------------
// K0 (16 blocks): (a) gain table gT[j=m*5+v][256 c] = F[c][m][v]/64, doubled
//     for v in {1,2,3}; (b) w_in hi/lo split; (c) w_out bf16 table.
// ---------------------------------------------------------------------------
__global__ void k_precompute(const float* __restrict__ F,
                             const float* __restrict__ w_in,
                             const float* __restrict__ w_out,
                             float* __restrict__ gT,
                             unsigned short* __restrict__ whi,
                             unsigned short* __restrict__ wlo,
                             unsigned short* __restrict__ wob)
{
    const int tid = threadIdx.x, bid = blockIdx.x;
    const int step = 16*256;

    for (int e = bid*256 + tid; e < 256*64; e += step) {
        float v = w_in[e];
        unsigned hu = f2bf_bits(v);
        whi[e] = (unsigned short)hu;
        wlo[e] = (unsigned short)f2bf_bits(v - bfbits2f(hu));
    }
    for (int e = bid*256 + tid; e < 64*128; e += step)
        wob[e] = (unsigned short)f2bf_bits(w_out[e]);

    for (int e = bid*256 + tid; e < 40*256; e += step) {
        const int j = e >> 8, c = e & 255;       // j = m*5+v
        const int v = j % 5;
        const float sc = (v == 0 || v == 4) ? 0.015625f : 0.03125f;
        gT[e] = F[c*40 + j] * sc;
    }
}

// ---------------------------------------------------------------------------
// K1: per (b, h, 64-col run): proj_in via MFMA (hi/lo bf16, 16 acc tiles in
// regs), ysT bf16 in LDS, per-thread 8x8 FFT conv (channel = tid), bf16
// chunk-blocked store s[b][c2/8][h][w][8ch].
// LDS union 33KB; launch_bounds(256,3) ~170 VGPR -> no spill.
// ---------------------------------------------------------------------------
__global__ __launch_bounds__(256, 3) void k1_proj_circ(
    const float* __restrict__ x,
    const unsigned short* __restrict__ whi,
    const unsigned short* __restrict__ wlo,
    const float* __restrict__ b_in,
    const float* __restrict__ gT,
    bf16* __restrict__ s)
{
    __shared__ __align__(16) unsigned short smem[64*258];   // 33,024 B
    unsigned short* xs_hi = smem;
    unsigned short* xs_lo = smem + 4096;
    unsigned short* ysT   = smem;

    const int tid = threadIdx.x;
    const int bid = blockIdx.x;
    const int run = bid & 3;
    const int h   = (bid >> 2) & 255;
    const int b   = bid >> 10;

    const float* xb = x + (long)b * CIN * HW + h * WW + run * 64;

    // stage x tile (64 cin x 64 px), hi/lo bf16 split, [px][cin] XOR-swizzled
#pragma unroll
    for (int i = 0; i < 16; ++i) {
        int e = i*256 + tid;
        int c = e >> 6, col = e & 63;
        float v = xb[(long)c * HW + col];
        unsigned hu = f2bf_bits(v);
        unsigned lu = f2bf_bits(v - bfbits2f(hu));
        const int sw = col*64 + (c ^ ((col & 7) << 3));
        xs_hi[sw] = (unsigned short)hu;
        xs_lo[sw] = (unsigned short)lu;
    }
    __syncthreads();

    const int wv = tid >> 6, lane = tid & 63;
    const int quad = lane >> 4, n16 = lane & 15;

    // proj MFMAs: all 4 nt-tiles, accumulators held in registers.
    f32x4 acc[4][4];
#pragma unroll
    for (int nt = 0; nt < 4; ++nt)
#pragma unroll
        for (int mt = 0; mt < 4; ++mt) acc[nt][mt] = (f32x4){0.f,0.f,0.f,0.f};

#pragma unroll
    for (int nt = 0; nt < 4; ++nt) {
        const int c2 = wv*64 + nt*16 + n16;
#pragma unroll
        for (int k = 0; k < 2; ++k) {
            const bf16x8 bh = *(const bf16x8*)&whi[c2*64 + k*32 + quad*8];
            const bf16x8 bl = *(const bf16x8*)&wlo[c2*64 + k*32 + quad*8];
#pragma unroll
            for (int mt = 0; mt < 4; ++mt) {
                const int o = (mt*16 + n16)*64 + (((k*4 + quad) ^ (n16 & 7)) << 3);
                const bf16x8 a_h = *(const bf16x8*)&xs_hi[o];
                const bf16x8 a_l = *(const bf16x8*)&xs_lo[o];
                acc[nt][mt] = __builtin_amdgcn_mfma_f32_16x16x32_bf16(a_h, bh, acc[nt][mt], 0, 0, 0);
                acc[nt][mt] = __builtin_amdgcn_mfma_f32_16x16x32_bf16(a_l, bh, acc[nt][mt], 0, 0, 0);
                acc[nt][mt] = __builtin_amdgcn_mfma_f32_16x16x32_bf16(a_h, bl, acc[nt][mt], 0, 0, 0);
            }
        }
    }
    __syncthreads();        // xs region dead; safe to overwrite with ysT

    // write ysT[u][c2] (stride 258) + bias
#pragma unroll
    for (int nt = 0; nt < 4; ++nt) {
        const int c2 = wv*64 + nt*16 + n16;
        const float bv = b_in[c2];
#pragma unroll
        for (int mt = 0; mt < 4; ++mt)
#pragma unroll
            for (int r = 0; r < 4; ++r) {
                int u = mt*16 + quad*4 + r;          // D row = quad*4 + reg
                ysT[u*258 + c2] = (unsigned short)f2bf_bits(acc[nt][mt][r] + bv);
            }
    }
    __syncthreads();

    // ---- per-thread 8x8 FFT conv: thread = channel tid (column private).
    float yr[8][8];
#pragma unroll
    for (int u = 0; u < 64; ++u)
        yr[u >> 3][u & 7] = bfbits2f((unsigned)ysT[u*258 + tid]);

    const float R2 = 0.70710678118654752f;

    // row forward rFFT8: yr[a] := [X0, X1r, X1i, X2r, X2i, X3r, X3i, X4]
#pragma unroll
    for (int a = 0; a < 8; ++a) {
        float x0=yr[a][0],x1=yr[a][1],x2=yr[a][2],x3=yr[a][3],
              x4=yr[a][4],x5=yr[a][5],x6=yr[a][6],x7=yr[a][7];
        float t0=x0+x4, t1=x0-x4, t2=x2+x6, t3=x2-x6;
        float u0=x1+x5, u1=x1-x5, u2=x3+x7, u3=x3-x7;
        float E0=t0+t2, E2=t0-t2, O0=u0+u2, O2=u0-u2;
        float rm=R2*(u1-u3), rp=R2*(u1+u3);
        yr[a][0]=E0+O0;                       // X0 (real)
        yr[a][7]=E0-O0;                       // X4 (real)
        yr[a][1]=t1+rm;  yr[a][2]=-t3-rp;     // X1
        yr[a][3]=E2;     yr[a][4]=-O2;        // X2 = E2 - i O2
        yr[a][5]=t1-rm;  yr[a][6]=t3-rp;      // X3
    }

    // columns 0 and 4 (real inputs): fwd cFFT8 -> gain -> inverse (conj
    // trick); result written back IN PLACE to yr[a][0] / yr[a][7].
#pragma unroll
    for (int cc = 0; cc < 2; ++cc) {
        float cr[8], ci[8];
#pragma unroll
        for (int a2 = 0; a2 < 8; ++a2) { cr[a2] = yr[a2][cc ? 7 : 0]; ci[a2] = 0.f; }
        fft8c(cr, ci);
#pragma unroll
        for (int m = 0; m < 8; ++m) {
            const float gv = gT[(m*5 + (cc ? 4 : 0))*256 + tid];
            cr[m] = cr[m]*gv; ci[m] = -(ci[m]*gv);     // conj for inverse
        }
        fft8c(cr, ci);
#pragma unroll
        for (int a2 = 0; a2 < 8; ++a2) { yr[a2][cc ? 7 : 0] = cr[a2]; }
    }

    // columns 1..3 (complex): fwd -> gain -> inverse, in place
#pragma unroll
    for (int v = 1; v <= 3; ++v) {
        float cr[8], ci[8];
#pragma unroll
        for (int a2 = 0; a2 < 8; ++a2) { cr[a2] = yr[a2][2*v-1]; ci[a2] = yr[a2][2*v]; }
        fft8c(cr, ci);
#pragma unroll
        for (int m = 0; m < 8; ++m) {
            const float gv = gT[(m*5 + v)*256 + tid];
            cr[m] = cr[m]*gv; ci[m] = -(ci[m]*gv);     // conj for inverse
        }
        fft8c(cr, ci);
#pragma unroll
        for (int a2 = 0; a2 < 8; ++a2) { yr[a2][2*v-1] = cr[a2]; yr[a2][2*v] = -ci[a2]; }
    }

    // row inverse (real output; x2 middle-bin weight folded into gT)
#pragma unroll
    for (int a = 0; a < 8; ++a) {
        float a0 = yr[a][0], a4 = yr[a][7];
        float T1r=yr[a][1], T1i=yr[a][2], T2r=yr[a][3], T2i=yr[a][4],
              T3r=yr[a][5], T3i=yr[a][6];
        float A0=a0+a4, A1=a0-a4;
        float Q0=T1r+T3r;
        float Q1=R2*((T1r-T1i)-(T3r+T3i));
        float Q2=T3i-T1i;
        float Q3=R2*((T3r-T3i)-(T1r+T1i));
        float B0=A0+T2r, B2=A0-T2r, B1=A1-T2i, B3=A1+T2i;
        ysT[(a*8+0)*258+tid]=(unsigned short)f2bf_bits(B0+Q0);
        ysT[(a*8+4)*258+tid]=(unsigned short)f2bf_bits(B0-Q0);
        ysT[(a*8+1)*258+tid]=(unsigned short)f2bf_bits(B1+Q1);
        ysT[(a*8+5)*258+tid]=(unsigned short)f2bf_bits(B1-Q1);
        ysT[(a*8+2)*258+tid]=(unsigned short)f2bf_bits(B2+Q2);
        ysT[(a*8+6)*258+tid]=(unsigned short)f2bf_bits(B2-Q2);
        ysT[(a*8+3)*258+tid]=(unsigned short)f2bf_bits(B3+Q3);
        ysT[(a*8+7)*258+tid]=(unsigned short)f2bf_bits(B3-Q3);
    }
    __syncthreads();

    // store: chunk-blocked layout s[b][chunk=c2/8][h][w][8ch]
    const int u   = tid & 63;
    const int rg2 = tid >> 6;          // 0..3
#pragma unroll
    for (int pass = 0; pass < 8; ++pass) {
        const int chunk = pass*4 + rg2;                       // 0..31
        const unsigned* yp = (const unsigned*)&ysT[u*258 + chunk*8];
        uint4 val = make_uint4(yp[0], yp[1], yp[2], yp[3]);
        *(uint4*)(s + ((((long)(b*32 + chunk)*HH + h)*WW) + run*64 + u)*8) = val;
    }
}

// ---------------------------------------------------------------------------
// K2 (unchanged from R12): dw3x3 + bias -> GELU gate -> MFMA proj_out.
// ---------------------------------------------------------------------------
__global__ __launch_bounds__(256) void k2_dw_gelu_out(
    const bf16* __restrict__ s, const float* __restrict__ w_dw,
    const float* __restrict__ b_dw,
    const unsigned short* __restrict__ wob,
    const float* __restrict__ b_out, float* __restrict__ out)
{
    __shared__ __align__(16) unsigned short gs[64*136];   // 17 KB, [px][c]

    const int tid = threadIdx.x;
    const int l   = ((blockIdx.x & 7) << 9) | (blockIdx.x >> 3);  // XCD swizzle
    const int run = l & 3;
    const int h   = (l >> 2) & 255;
    const int b   = l >> 10;
    const int wl  = tid & 63, rg = tid >> 6;
    const int w   = run*64 + wl;

#pragma unroll
    for (int i = 0; i < 4; ++i) {
        const int chunk = __builtin_amdgcn_readfirstlane(rg + 4*i);   // 0..15, uniform
        const int c0 = chunk*8;                                        // 0..120
        const bf16* pb1 = s + (long)(b*32 + chunk     ) * HW * 8;
        const bf16* pb2 = s + (long)(b*32 + chunk + 16) * HW * 8;

        float t1[8], t2[8];
#pragma unroll
        for (int j = 0; j < 8; ++j) { t1[j] = b_dw[c0+j]; t2[j] = b_dw[c0+128+j]; }

#pragma unroll
        for (int dy = 0; dy < 3; ++dy) {
            const int hy = h + dy - 1;
            if ((unsigned)hy >= HH) continue;          // wave-uniform
#pragma unroll
            for (int dx = 0; dx < 3; ++dx) {
                const int wx = w + dx - 1;
                if ((unsigned)wx < WW) {               // diverges only at image edge
                    const int off = (hy*WW + wx) << 3; // element offset, fits int
                    uint4 v1 = *(const uint4*)(pb1 + off);
                    uint4 v2 = *(const uint4*)(pb2 + off);
                    float f1[8], f2[8];
                    unpack8(v1, f1); unpack8(v2, f2);
#pragma unroll
                    for (int j = 0; j < 8; ++j) {
                        t1[j] += f1[j] * w_dw[(c0+j)*9       + dy*3 + dx];
                        t2[j] += f2[j] * w_dw[(c0+128+j)*9   + dy*3 + dx];
                    }
                }
            }
        }
        unsigned r4[4];
#pragma unroll
        for (int j = 0; j < 4; ++j) {
            float ga = gelu_exact(t1[2*j])   * t2[2*j];
            float gb = gelu_exact(t1[2*j+1]) * t2[2*j+1];
            r4[j] = f2bf_bits(ga) | (f2bf_bits(gb) << 16);
        }
        *(uint4*)&gs[wl*136 + c0] = make_uint4(r4[0], r4[1], r4[2], r4[3]);
    }
    __syncthreads();

    const int quad = wl >> 4, n16 = wl & 15;
    const int px   = rg*16 + n16;

    f32x4 acc[4];
#pragma unroll
    for (int mt = 0; mt < 4; ++mt) acc[mt] = (f32x4){0.f,0.f,0.f,0.f};

#pragma unroll
    for (int ks = 0; ks < 4; ++ks) {
        const bf16x8 bfrag = *(const bf16x8*)&gs[px*136 + ks*32 + quad*8];
#pragma unroll
        for (int mt = 0; mt < 4; ++mt) {
            const bf16x8 afrag = *(const bf16x8*)&wob[(mt*16 + n16)*128 + ks*32 + quad*8];
            acc[mt] = __builtin_amdgcn_mfma_f32_16x16x32_bf16(afrag, bfrag, acc[mt], 0, 0, 0);
        }
    }

    float* op = out + (long)b * CIN * HW + h * WW + run*64 + rg*16 + n16;
#pragma unroll
    for (int mt = 0; mt < 4; ++mt)
#pragma unroll
        for (int r = 0; r < 4; ++r) {
            const int c_out = mt*16 + quad*4 + r;
            op[(long)c_out * HW] = acc[mt][r] + b_out[c_out];
        }
}

// ---------------------------------------------------------------------------
extern "C" void kernel_launch(void* const* d_in, const int* in_sizes, int n_in,
                              void* d_out, int out_size, void* d_ws, size_t ws_size,
                              hipStream_t stream) {
    const float* x     = (const float*)d_in[0];
    const float* w_in  = (const float*)d_in[1];
    const float* b_in  = (const float*)d_in[2];
    const float* ff    = (const float*)d_in[3];
    const float* w_dw  = (const float*)d_in[4];
    const float* b_dw  = (const float*)d_in[5];
    const float* w_out = (const float*)d_in[6];
    const float* b_out = (const float*)d_in[7];
    float* out = (float*)d_out;

    // d_ws layout (R12 footprint): gT [0,40K) | wob [64K,80K) | s [80K, +128MB)
    char* ws = (char*)d_ws;
    float*          gT  = (float*)ws;
    unsigned short* wob = (unsigned short*)(ws + 65536);
    bf16*           s   = (bf16*)         (ws + 81920);

    // whi/wlo in d_out: only k1 reads them; k1 retires (stream order) before
    // k2 overwrites out. Pattern proven R6-R18.
    unsigned short* whi = (unsigned short*)d_out;       // 32 KB
    unsigned short* wlo = whi + 256*64;                 // 32 KB

    hipLaunchKernelGGL(k_precompute,   dim3(16),   dim3(256), 0, stream,
                       ff, w_in, w_out, gT, whi, wlo, wob);
    hipLaunchKernelGGL(k1_proj_circ,   dim3(4096), dim3(256), 0, stream,
                       x, whi, wlo, b_in, gT, s);
    hipLaunchKernelGGL(k2_dw_gelu_out, dim3(4096), dim3(256), 0, stream,
                       s, w_dw, b_dw, wob, b_out, out);
}

// Round 14
// 288.316 us; speedup vs baseline: 2.5780x; 1.1123x over previous
//
#include <hip/hip_runtime.h>
#include <hip/hip_bf16.h>

// DFFN fused implementation. R20 = R19 (best 320.7us) + k2 dx-shuffle taps.
// R19 counters: k2 now top dispatch (~167us): VALUBusy 42%, MfmaUtil 1%,
// HBM 10% -> L3-BW bound: 9x tap re-read of s = ~1.2GB through Infinity
// Cache per dispatch. Fix: within a wave, lanes = consecutive w px, so the
// dx=+-1 tap values are the neighbors' center values -> per (task,dy) load
// ONLY the center row (2x16B + two single-lane edge loads) and derive dx=+-1
// via __shfl_up/down (16 dword-shuffles) with lane-0/63 zero-padding fixups
// (== the old per-lane wx bounds check). ~2.9x less L3 traffic. Math
// identical. k0/k1 unchanged from R19 (PASSED, absmax 2.44e-4).
// Pipeline: proj_in(1x1 MFMA hi/lo bf16) -> per-channel 8x8 circular conv
// (per-thread radix-2 real FFT) -> dw3x3 -> GELU gate -> proj_out(MFMA).
// s: bf16 [b][c2/8][h][w][8ch].

#define BATCH 4
#define CIN   64
#define C2    256
#define HH    256
#define WW    256
#define HW    (HH*WW)

using bf16 = __hip_bfloat16;
typedef short bf16x8 __attribute__((ext_vector_type(8)));
typedef float f32x4  __attribute__((ext_vector_type(4)));

__device__ __forceinline__ unsigned f2bf_bits(float v){
    unsigned u = __float_as_uint(v);
    return (u + 0x7fffu + ((u >> 16) & 1u)) >> 16;          // RNE
}
__device__ __forceinline__ float bfbits2f(unsigned hu){ return __uint_as_float(hu << 16); }

__device__ __forceinline__ void unpack8(uint4 v, float* f) {
    unsigned a0 = v.x, a1 = v.y, a2 = v.z, a3 = v.w;
    f[0] = __uint_as_float(a0 << 16); f[1] = __uint_as_float(a0 & 0xffff0000u);
    f[2] = __uint_as_float(a1 << 16); f[3] = __uint_as_float(a1 & 0xffff0000u);
    f[4] = __uint_as_float(a2 << 16); f[5] = __uint_as_float(a2 & 0xffff0000u);
    f[6] = __uint_as_float(a3 << 16); f[7] = __uint_as_float(a3 & 0xffff0000u);
}

// GELU(v) = 0.5*v*(1+erf(v/sqrt2)), erf via A&S 7.1.26 (|eps| <= 1.5e-7).
__device__ __forceinline__ float gelu_exact(float v){
    float z  = v * 0.7071067811865476f;
    float ax = fabsf(z);
    float t  = 1.0f / fmaf(0.3275911f, ax, 1.0f);
    float p  = t * fmaf(t, fmaf(t, fmaf(t, fmaf(t, 1.061405429f, -1.453152027f),
                                        1.421413741f), -0.284496736f), 0.254829592f);
    float e  = __expf(-ax*ax);
    float er = fmaf(-p, e, 1.0f);                // erf(|z|)
    er = copysignf(er, z);
    return 0.5f * v * (1.0f + er);
}

// Complex 8-point DIT FFT (W = e^{-2pi i/8}), in-place, natural order.
__device__ __forceinline__ void fft8c(float* re, float* im){
    const float R2 = 0.70710678118654752f;
    float t0r=re[0]+re[4], t0i=im[0]+im[4];
    float t1r=re[0]-re[4], t1i=im[0]-im[4];
    float t2r=re[2]+re[6], t2i=im[2]+im[6];
    float t3r=re[2]-re[6], t3i=im[2]-im[6];
    float E0r=t0r+t2r, E0i=t0i+t2i;
    float E2r=t0r-t2r, E2i=t0i-t2i;
    float E1r=t1r+t3i, E1i=t1i-t3r;          // t1 - i t3
    float E3r=t1r-t3i, E3i=t1i+t3r;          // t1 + i t3
    float u0r=re[1]+re[5], u0i=im[1]+im[5];
    float u1r=re[1]-re[5], u1i=im[1]-im[5];
    float u2r=re[3]+re[7], u2i=im[3]+im[7];
    float u3r=re[3]-re[7], u3i=im[3]-im[7];
    float O0r=u0r+u2r, O0i=u0i+u2i;
    float O2r=u0r-u2r, O2i=u0i-u2i;
    float O1r=u1r+u3i, O1i=u1i-u3r;
    float O3r=u1r-u3i, O3i=u1i+u3r;
    float w1r=R2*(O1r+O1i), w1i=R2*(O1i-O1r);    // W^1 O1
    float w3r=R2*(O3i-O3r), w3i=-R2*(O3r+O3i);   // W^3 O3
    re[0]=E0r+O0r; im[0]=E0i+O0i;
    re[4]=E0r-O0r; im[4]=E0i-O0i;
    re[1]=E1r+w1r; im[1]=E1i+w1i;
    re[5]=E1r-w1r; im[5]=E1i-w1i;
    re[2]=E2r+O2i; im[2]=E2i-O2r;                // E2 - i O2
    re[6]=E2r-O2i; im[6]=E2i+O2r;
    re[3]=E3r+w3r; im[3]=E3i+w3i;
    re[7]=E3r-w3r; im[7]=E3i-w3i;
}

// ---------------------------------------------------------------------------
// K0 (16 blocks): (a) gain table gT[j=m*5+v][256 c] = F[c][m][v]/64, doubled
//     for v in {1,2,3}; (b) w_in hi/lo split; (c) w_out bf16 table.
// ---------------------------------------------------------------------------
__global__ void k_precompute(const float* __restrict__ F,
                             const float* __restrict__ w_in,
                             const float* __restrict__ w_out,
                             float* __restrict__ gT,
                             unsigned short* __restrict__ whi,
                             unsigned short* __restrict__ wlo,
                             unsigned short* __restrict__ wob)
{
    const int tid = threadIdx.x, bid = blockIdx.x;
    const int step = 16*256;

    for (int e = bid*256 + tid; e < 256*64; e += step) {
        float v = w_in[e];
        unsigned hu = f2bf_bits(v);
        whi[e] = (unsigned short)hu;
        wlo[e] = (unsigned short)f2bf_bits(v - bfbits2f(hu));
    }
    for (int e = bid*256 + tid; e < 64*128; e += step)
        wob[e] = (unsigned short)f2bf_bits(w_out[e]);

    for (int e = bid*256 + tid; e < 40*256; e += step) {
        const int j = e >> 8, c = e & 255;       // j = m*5+v
        const int v = j % 5;
        const float sc = (v == 0 || v == 4) ? 0.015625f : 0.03125f;
        gT[e] = F[c*40 + j] * sc;
    }
}

// ---------------------------------------------------------------------------
// K1 (unchanged from R19): proj_in via MFMA + per-thread 8x8 FFT conv.
// ---------------------------------------------------------------------------
__global__ __launch_bounds__(256, 3) void k1_proj_circ(
    const float* __restrict__ x,
    const unsigned short* __restrict__ whi,
    const unsigned short* __restrict__ wlo,
    const float* __restrict__ b_in,
    const float* __restrict__ gT,
    bf16* __restrict__ s)
{
    __shared__ __align__(16) unsigned short smem[64*258];   // 33,024 B
    unsigned short* xs_hi = smem;
    unsigned short* xs_lo = smem + 4096;
    unsigned short* ysT   = smem;

    const int tid = threadIdx.x;
    const int bid = blockIdx.x;
    const int run = bid & 3;
    const int h   = (bid >> 2) & 255;
    const int b   = bid >> 10;

    const float* xb = x + (long)b * CIN * HW + h * WW + run * 64;

#pragma unroll
    for (int i = 0; i < 16; ++i) {
        int e = i*256 + tid;
        int c = e >> 6, col = e & 63;
        float v = xb[(long)c * HW + col];
        unsigned hu = f2bf_bits(v);
        unsigned lu = f2bf_bits(v - bfbits2f(hu));
        const int sw = col*64 + (c ^ ((col & 7) << 3));
        xs_hi[sw] = (unsigned short)hu;
        xs_lo[sw] = (unsigned short)lu;
    }
    __syncthreads();

    const int wv = tid >> 6, lane = tid & 63;
    const int quad = lane >> 4, n16 = lane & 15;

    f32x4 acc[4][4];
#pragma unroll
    for (int nt = 0; nt < 4; ++nt)
#pragma unroll
        for (int mt = 0; mt < 4; ++mt) acc[nt][mt] = (f32x4){0.f,0.f,0.f,0.f};

#pragma unroll
    for (int nt = 0; nt < 4; ++nt) {
        const int c2 = wv*64 + nt*16 + n16;
#pragma unroll
        for (int k = 0; k < 2; ++k) {
            const bf16x8 bh = *(const bf16x8*)&whi[c2*64 + k*32 + quad*8];
            const bf16x8 bl = *(const bf16x8*)&wlo[c2*64 + k*32 + quad*8];
#pragma unroll
            for (int mt = 0; mt < 4; ++mt) {
                const int o = (mt*16 + n16)*64 + (((k*4 + quad) ^ (n16 & 7)) << 3);
                const bf16x8 a_h = *(const bf16x8*)&xs_hi[o];
                const bf16x8 a_l = *(const bf16x8*)&xs_lo[o];
                acc[nt][mt] = __builtin_amdgcn_mfma_f32_16x16x32_bf16(a_h, bh, acc[nt][mt], 0, 0, 0);
                acc[nt][mt] = __builtin_amdgcn_mfma_f32_16x16x32_bf16(a_l, bh, acc[nt][mt], 0, 0, 0);
                acc[nt][mt] = __builtin_amdgcn_mfma_f32_16x16x32_bf16(a_h, bl, acc[nt][mt], 0, 0, 0);
            }
        }
    }
    __syncthreads();        // xs region dead; safe to overwrite with ysT

#pragma unroll
    for (int nt = 0; nt < 4; ++nt) {
        const int c2 = wv*64 + nt*16 + n16;
        const float bv = b_in[c2];
#pragma unroll
        for (int mt = 0; mt < 4; ++mt)
#pragma unroll
            for (int r = 0; r < 4; ++r) {
                int u = mt*16 + quad*4 + r;
                ysT[u*258 + c2] = (unsigned short)f2bf_bits(acc[nt][mt][r] + bv);
            }
    }
    __syncthreads();

    // per-thread 8x8 FFT conv (channel = tid)
    float yr[8][8];
#pragma unroll
    for (int u = 0; u < 64; ++u)
        yr[u >> 3][u & 7] = bfbits2f((unsigned)ysT[u*258 + tid]);

    const float R2 = 0.70710678118654752f;

#pragma unroll
    for (int a = 0; a < 8; ++a) {
        float x0=yr[a][0],x1=yr[a][1],x2=yr[a][2],x3=yr[a][3],
              x4=yr[a][4],x5=yr[a][5],x6=yr[a][6],x7=yr[a][7];
        float t0=x0+x4, t1=x0-x4, t2=x2+x6, t3=x2-x6;
        float u0=x1+x5, u1=x1-x5, u2=x3+x7, u3=x3-x7;
        float E0=t0+t2, E2=t0-t2, O0=u0+u2, O2=u0-u2;
        float rm=R2*(u1-u3), rp=R2*(u1+u3);
        yr[a][0]=E0+O0;
        yr[a][7]=E0-O0;
        yr[a][1]=t1+rm;  yr[a][2]=-t3-rp;
        yr[a][3]=E2;     yr[a][4]=-O2;
        yr[a][5]=t1-rm;  yr[a][6]=t3-rp;
    }

#pragma unroll
    for (int cc = 0; cc < 2; ++cc) {
        float cr[8], ci[8];
#pragma unroll
        for (int a2 = 0; a2 < 8; ++a2) { cr[a2] = yr[a2][cc ? 7 : 0]; ci[a2] = 0.f; }
        fft8c(cr, ci);
#pragma unroll
        for (int m = 0; m < 8; ++m) {
            const float gv = gT[(m*5 + (cc ? 4 : 0))*256 + tid];
            cr[m] = cr[m]*gv; ci[m] = -(ci[m]*gv);
        }
        fft8c(cr, ci);
#pragma unroll
        for (int a2 = 0; a2 < 8; ++a2) { yr[a2][cc ? 7 : 0] = cr[a2]; }
    }

#pragma unroll
    for (int v = 1; v <= 3; ++v) {
        float cr[8], ci[8];
#pragma unroll
        for (int a2 = 0; a2 < 8; ++a2) { cr[a2] = yr[a2][2*v-1]; ci[a2] = yr[a2][2*v]; }
        fft8c(cr, ci);
#pragma unroll
        for (int m = 0; m < 8; ++m) {
            const float gv = gT[(m*5 + v)*256 + tid];
            cr[m] = cr[m]*gv; ci[m] = -(ci[m]*gv);
        }
        fft8c(cr, ci);
#pragma unroll
        for (int a2 = 0; a2 < 8; ++a2) { yr[a2][2*v-1] = cr[a2]; yr[a2][2*v] = -ci[a2]; }
    }

#pragma unroll
    for (int a = 0; a < 8; ++a) {
        float a0 = yr[a][0], a4 = yr[a][7];
        float T1r=yr[a][1], T1i=yr[a][2], T2r=yr[a][3], T2i=yr[a][4],
              T3r=yr[a][5], T3i=yr[a][6];
        float A0=a0+a4, A1=a0-a4;
        float Q0=T1r+T3r;
        float Q1=R2*((T1r-T1i)-(T3r+T3i));
        float Q2=T3i-T1i;
        float Q3=R2*((T3r-T3i)-(T1r+T1i));
        float B0=A0+T2r, B2=A0-T2r, B1=A1-T2i, B3=A1+T2i;
        ysT[(a*8+0)*258+tid]=(unsigned short)f2bf_bits(B0+Q0);
        ysT[(a*8+4)*258+tid]=(unsigned short)f2bf_bits(B0-Q0);
        ysT[(a*8+1)*258+tid]=(unsigned short)f2bf_bits(B1+Q1);
        ysT[(a*8+5)*258+tid]=(unsigned short)f2bf_bits(B1-Q1);
        ysT[(a*8+2)*258+tid]=(unsigned short)f2bf_bits(B2+Q2);
        ysT[(a*8+6)*258+tid]=(unsigned short)f2bf_bits(B2-Q2);
        ysT[(a*8+3)*258+tid]=(unsigned short)f2bf_bits(B3+Q3);
        ysT[(a*8+7)*258+tid]=(unsigned short)f2bf_bits(B3-Q3);
    }
    __syncthreads();

    const int u   = tid & 63;
    const int rg2 = tid >> 6;
#pragma unroll
    for (int pass = 0; pass < 8; ++pass) {
        const int chunk = pass*4 + rg2;                       // 0..31
        const unsigned* yp = (const unsigned*)&ysT[u*258 + chunk*8];
        uint4 val = make_uint4(yp[0], yp[1], yp[2], yp[3]);
        *(uint4*)(s + ((((long)(b*32 + chunk)*HH + h)*WW) + run*64 + u)*8) = val;
    }
}

// ---------------------------------------------------------------------------
// K2 (R20): dw3x3 taps via lane shuffle — per (task,dy) load only the center
// row; dx=+-1 views come from neighbor lanes (+ edge loads / zero-pad).
// ---------------------------------------------------------------------------
__global__ __launch_bounds__(256) void k2_dw_gelu_out(
    const bf16* __restrict__ s, const float* __restrict__ w_dw,
    const float* __restrict__ b_dw,
    const unsigned short* __restrict__ wob,
    const float* __restrict__ b_out, float* __restrict__ out)
{
    __shared__ __align__(16) unsigned short gs[64*136];   // 17 KB, [px][c]

    const int tid = threadIdx.x;
    const int l   = ((blockIdx.x & 7) << 9) | (blockIdx.x >> 3);  // XCD swizzle
    const int run = l & 3;
    const int h   = (l >> 2) & 255;
    const int b   = l >> 10;
    const int wl  = tid & 63, rg = tid >> 6;
    const int w   = run*64 + wl;

#pragma unroll
    for (int i = 0; i < 4; ++i) {
        const int chunk = __builtin_amdgcn_readfirstlane(rg + 4*i);   // 0..15, uniform
        const int c0 = chunk*8;                                        // 0..120
        const bf16* pb1 = s + (long)(b*32 + chunk     ) * HW * 8;
        const bf16* pb2 = s + (long)(b*32 + chunk + 16) * HW * 8;

        float t1[8], t2[8];
#pragma unroll
        for (int j = 0; j < 8; ++j) { t1[j] = b_dw[c0+j]; t2[j] = b_dw[c0+128+j]; }

#pragma unroll
        for (int dy = 0; dy < 3; ++dy) {
            const int hy = h + dy - 1;
            if ((unsigned)hy >= HH) continue;          // wave-uniform
            const int off = (hy*WW + w) << 3;          // center element offset

            uint4 c1 = *(const uint4*)(pb1 + off);
            uint4 c2 = *(const uint4*)(pb2 + off);

            // edge values (lane 0 / lane 63 only); zero = SAME zero-padding
            uint4 e1 = make_uint4(0,0,0,0), e2 = e1, g1 = e1, g2 = e1;
            if (wl == 0 && w != 0) {
                e1 = *(const uint4*)(pb1 + off - 8);
                e2 = *(const uint4*)(pb2 + off - 8);
            }
            if (wl == 63 && w != WW-1) {
                g1 = *(const uint4*)(pb1 + off + 8);
                g2 = *(const uint4*)(pb2 + off + 8);
            }

            // dx=-1 view: lane l <- lane l-1's center
            uint4 m1, m2, p1, p2;
            m1.x = __shfl_up((int)c1.x, 1, 64); m1.y = __shfl_up((int)c1.y, 1, 64);
            m1.z = __shfl_up((int)c1.z, 1, 64); m1.w = __shfl_up((int)c1.w, 1, 64);
            m2.x = __shfl_up((int)c2.x, 1, 64); m2.y = __shfl_up((int)c2.y, 1, 64);
            m2.z = __shfl_up((int)c2.z, 1, 64); m2.w = __shfl_up((int)c2.w, 1, 64);
            // dx=+1 view: lane l <- lane l+1's center
            p1.x = __shfl_down((int)c1.x, 1, 64); p1.y = __shfl_down((int)c1.y, 1, 64);
            p1.z = __shfl_down((int)c1.z, 1, 64); p1.w = __shfl_down((int)c1.w, 1, 64);
            p2.x = __shfl_down((int)c2.x, 1, 64); p2.y = __shfl_down((int)c2.y, 1, 64);
            p2.z = __shfl_down((int)c2.z, 1, 64); p2.w = __shfl_down((int)c2.w, 1, 64);
            if (wl == 0)  { m1 = e1; m2 = e2; }
            if (wl == 63) { p1 = g1; p2 = g2; }

            float f1[8], f2[8];
            // dx = -1 -> weight dy*3+0
            unpack8(m1, f1); unpack8(m2, f2);
#pragma unroll
            for (int j = 0; j < 8; ++j) {
                t1[j] += f1[j] * w_dw[(c0+j)*9     + dy*3 + 0];
                t2[j] += f2[j] * w_dw[(c0+128+j)*9 + dy*3 + 0];
            }
            // dx = 0 -> weight dy*3+1
            unpack8(c1, f1); unpack8(c2, f2);
#pragma unroll
            for (int j = 0; j < 8; ++j) {
                t1[j] += f1[j] * w_dw[(c0+j)*9     + dy*3 + 1];
                t2[j] += f2[j] * w_dw[(c0+128+j)*9 + dy*3 + 1];
            }
            // dx = +1 -> weight dy*3+2
            unpack8(p1, f1); unpack8(p2, f2);
#pragma unroll
            for (int j = 0; j < 8; ++j) {
                t1[j] += f1[j] * w_dw[(c0+j)*9     + dy*3 + 2];
                t2[j] += f2[j] * w_dw[(c0+128+j)*9 + dy*3 + 2];
            }
        }

        unsigned r4[4];
#pragma unroll
        for (int j = 0; j < 4; ++j) {
            float ga = gelu_exact(t1[2*j])   * t2[2*j];
            float gb = gelu_exact(t1[2*j+1]) * t2[2*j+1];
            r4[j] = f2bf_bits(ga) | (f2bf_bits(gb) << 16);
        }
        *(uint4*)&gs[wl*136 + c0] = make_uint4(r4[0], r4[1], r4[2], r4[3]);
    }
    __syncthreads();

    const int quad = wl >> 4, n16 = wl & 15;
    const int px   = rg*16 + n16;

    f32x4 acc[4];
#pragma unroll
    for (int mt = 0; mt < 4; ++mt) acc[mt] = (f32x4){0.f,0.f,0.f,0.f};

#pragma unroll
    for (int ks = 0; ks < 4; ++ks) {
        const bf16x8 bfrag = *(const bf16x8*)&gs[px*136 + ks*32 + quad*8];
#pragma unroll
        for (int mt = 0; mt < 4; ++mt) {
            const bf16x8 afrag = *(const bf16x8*)&wob[(mt*16 + n16)*128 + ks*32 + quad*8];
            acc[mt] = __builtin_amdgcn_mfma_f32_16x16x32_bf16(afrag, bfrag, acc[mt], 0, 0, 0);
        }
    }

    float* op = out + (long)b * CIN * HW + h * WW + run*64 + rg*16 + n16;
#pragma unroll
    for (int mt = 0; mt < 4; ++mt)
#pragma unroll
        for (int r = 0; r < 4; ++r) {
            const int c_out = mt*16 + quad*4 + r;
            op[(long)c_out * HW] = acc[mt][r] + b_out[c_out];
        }
}

// ---------------------------------------------------------------------------
extern "C" void kernel_launch(void* const* d_in, const int* in_sizes, int n_in,
                              void* d_out, int out_size, void* d_ws, size_t ws_size,
                              hipStream_t stream) {
    const float* x     = (const float*)d_in[0];
    const float* w_in  = (const float*)d_in[1];
    const float* b_in  = (const float*)d_in[2];
    const float* ff    = (const float*)d_in[3];
    const float* w_dw  = (const float*)d_in[4];
    const float* b_dw  = (const float*)d_in[5];
    const float* w_out = (const float*)d_in[6];
    const float* b_out = (const float*)d_in[7];
    float* out = (float*)d_out;

    // d_ws layout (R12 footprint): gT [0,40K) | wob [64K,80K) | s [80K, +128MB)
    char* ws = (char*)d_ws;
    float*          gT  = (float*)ws;
    unsigned short* wob = (unsigned short*)(ws + 65536);
    bf16*           s   = (bf16*)         (ws + 81920);

    // whi/wlo in d_out: only k1 reads them; k1 retires (stream order) before
    // k2 overwrites out. Pattern proven R6-R19.
    unsigned short* whi = (unsigned short*)d_out;       // 32 KB
    unsigned short* wlo = whi + 256*64;                 // 32 KB

    hipLaunchKernelGGL(k_precompute,   dim3(16),   dim3(256), 0, stream,
                       ff, w_in, w_out, gT, whi, wlo, wob);
    hipLaunchKernelGGL(k1_proj_circ,   dim3(4096), dim3(256), 0, stream,
                       x, whi, wlo, b_in, gT, s);
    hipLaunchKernelGGL(k2_dw_gelu_out, dim3(4096), dim3(256), 0, stream,
                       s, w_dw, b_dw, wob, b_out, out);
}